// Round 4
// baseline (156.735 us; speedup 1.0000x reference)
//
#include <hip/hip_runtime.h>
#include <math.h>

#define TN 8192
#define AN 128
#define NW20 (TN - 20)
#define NW10 (TN - 10)
#define GRID 512
#define NGRAM 128
#define NFOLD 64
#define FOLD0 (GRID - NFOLD)   // 448

#define MAGICG 0x5AFE0601u
#define MAGICA 0x5AFE0A01u
#define MAGICB 0x5AFE0B01u

// ---- workspace double-layout ----
#define WS_STD0 0
#define WS_STDL 1
#define WS_SPEC 8            // 64*3 per-fold-block {sum, sumabs, trace}
#define WS_BLK  200          // 512*5 per-block {sumstd, conc, cnt20, sum10, sum10l5}
#define WS_DEND 2816

struct __align__(16) SMem {
  union {
    float stage[8][AN];                          // gram staging
    struct { double muS[AN]; double dS[AN];
             double r0[256], r1[256], r2[256]; } fold;
    struct { double s0[256], s1[256], s2[256], s3[256], s4[256]; } scal;
    struct { unsigned short cS[AN * 130];
             float vv[AN]; float prt[256]; float un[AN]; float red[AN]; } spec;
    struct { float f[2 * AN]; float h1[AN]; float h2[64]; float lg[4]; } mlp;
  } u;
  double tacc[4][5];
  double tiny[8];
};

// rolling off-diag corr, 4 consecutive windows per wave from one register strip.
// Butterfly-with-compression identical to the r1-r3 verified code (absmax 7e-9).
template <int W>
__device__ __forceinline__ void roll_strip4(const float* __restrict__ x,
                                            int s0, int nwin, int lane,
                                            double& accA, double& accB) {
  constexpr int NR = W + 3;
  float a0[NR], a1[NR];
#pragma unroll
  for (int t = 0; t < NR; ++t) {
    int r = s0 + t; r = (r < TN) ? r : (TN - 1);
    a0[t] = x[(size_t)r * AN + lane];
    a1[t] = x[(size_t)r * AN + lane + 64];
  }
#pragma unroll
  for (int w4 = 0; w4 < 4; ++w4) {
    int s = s0 + w4;
    if (s < nwin) {
      float sf0 = 0.f, sf1 = 0.f;
#pragma unroll
      for (int t = 0; t < W; ++t) { sf0 += a0[w4 + t]; sf1 += a1[w4 + t]; }
      float mu0 = sf0 / W, mu1 = sf1 / W;
      float v0 = 0.f, v1 = 0.f;
#pragma unroll
      for (int t = 0; t < W; ++t) {
        float d0 = a0[w4 + t] - mu0, d1 = a1[w4 + t] - mu1;
        v0 += d0 * d0; v1 += d1 * d1;
      }
      float i0 = 1.0f / sqrtf(v0), i1 = 1.0f / sqrtf(v1);
      float q[W];
#pragma unroll
      for (int t = 0; t < W; ++t)
        q[t] = (a0[w4 + t] - mu0) * i0 + (a1[w4 + t] - mu1) * i1;
      int n = W;
#pragma unroll
      for (int o = 1; o <= 32; o <<= 1) {
#pragma unroll
        for (int k = 0; k < n; ++k) q[k] += __shfl_xor(q[k], o);
        if (n > 1) {
          int nh = n >> 1;
          bool hi = (lane & o) != 0;
#pragma unroll
          for (int k = 0; k < nh; ++k) q[k] = hi ? q[2 * k + 1] : q[2 * k];
          if (n & 1) { q[nh] = q[2 * nh]; n = nh + 1; } else { n = nh; }
        }
      }
      float alpha = (W == 20) ? ((lane & 16) ? 0.125f : 0.5f)
                              : ((lane & 8) ? 0.0625f : 0.25f);
      float r = q[0] * q[0] * alpha;
#pragma unroll
      for (int o = 32; o; o >>= 1) r += __shfl_xor(r, o);
      if (lane == 0) {
        double off = ((double)r - (double)AN) / ((double)AN * (AN - 1));
        if (W == 20) {
          accA += (off > 0.7) ? 1.0 : 0.0;
        } else {
          accA += off;
          if (s >= TN - W - 5) accB += off;
        }
      }
    }
  }
}

__global__ void __launch_bounds__(256, 2) k_all(
    const float* __restrict__ x, const float* __restrict__ pos,
    const float* __restrict__ w1, const float* __restrict__ b1,
    const float* __restrict__ gamma, const float* __restrict__ beta,
    const float* __restrict__ w2, const float* __restrict__ b2,
    const float* __restrict__ w3, const float* __restrict__ b3,
    double* __restrict__ wsd, float* __restrict__ corr,
    float* __restrict__ pc, float* __restrict__ pdg, float* __restrict__ pg,
    unsigned int* __restrict__ flagG, unsigned int* __restrict__ flagA,
    unsigned int* __restrict__ flagB, float* __restrict__ out) {
  __shared__ SMem sm;
  const int b = blockIdx.x;
  const int tid = threadIdx.x;
  const int lane = tid & 63;
  const int w = tid >> 6;

  // ================= phase A1: gram slices (blocks 0..127) =============
  if (b < NGRAM) {
    int i0 = (tid >> 4) * 8;
    int j0 = (tid & 15) * 8;
    int lrow = tid >> 5;
    int lcol = (tid & 31) * 4;
    const float* xs = x + (size_t)b * 64 * AN;
    float acc[8][8];
#pragma unroll
    for (int a = 0; a < 8; ++a)
#pragma unroll
      for (int c = 0; c < 8; ++c) acc[a][c] = 0.f;
    float4 v = *(const float4*)(xs + lrow * AN + lcol);
    for (int it = 0; it < 8; ++it) {
      __syncthreads();
      *(float4*)(&sm.u.stage[lrow][lcol]) = v;
      __syncthreads();
      if (it + 1 < 8)
        v = *(const float4*)(xs + ((it + 1) * 8 + lrow) * AN + lcol);
#pragma unroll
      for (int r = 0; r < 8; ++r) {
        float aa[8], bb[8];
        *(float4*)(aa) = *(const float4*)(&sm.u.stage[r][i0]);
        *(float4*)(aa + 4) = *(const float4*)(&sm.u.stage[r][i0 + 4]);
        *(float4*)(bb) = *(const float4*)(&sm.u.stage[r][j0]);
        *(float4*)(bb + 4) = *(const float4*)(&sm.u.stage[r][j0 + 4]);
#pragma unroll
        for (int ai = 0; ai < 8; ++ai)
#pragma unroll
          for (int bj = 0; bj < 8; ++bj)
            acc[ai][bj] = fmaf(aa[ai], bb[bj], acc[ai][bj]);
      }
    }
    float* dst = pg + (size_t)b * (AN * AN);
#pragma unroll
    for (int ai = 0; ai < 8; ++ai)
#pragma unroll
      for (int bj = 0; bj < 8; bj += 4)
        *(float4*)(dst + (i0 + ai) * AN + j0 + bj) =
            make_float4(acc[ai][bj], acc[ai][bj + 1], acc[ai][bj + 2],
                        acc[ai][bj + 3]);
    if ((tid >> 4) == (tid & 15)) {
#pragma unroll
      for (int k = 0; k < 8; ++k) pdg[b * AN + i0 + k] = acc[k][k];
    }
    if (tid < AN) {
      float cs = 0.f;
      for (int r = 0; r < 64; ++r) cs += xs[r * AN + tid];
      pc[b * AN + tid] = cs;
    }
    __syncthreads();
    if (tid == 0) {
      __threadfence();
      __hip_atomic_store(&flagG[b], MAGICG, __ATOMIC_RELEASE,
                         __HIP_MEMORY_SCOPE_AGENT);
    }
  }

  // ====== phase A2: rowstats + rolling windows (all 512 blocks) ========
  double a_sstd = 0.0, a_conc = 0.0, a_c20 = 0.0, a_s10 = 0.0, a_s10l5 = 0.0;
  for (int rr = 0; rr < 4; ++rr) {
    int t = b * 16 + w * 4 + rr;
    const float* row = x + (size_t)t * AN;
    float x0 = row[lane], x1 = row[lane + 64];
    float s = x0 + x1;
#pragma unroll
    for (int o = 32; o; o >>= 1) s += __shfl_xor(s, o);
    float mean = s * (1.0f / AN);
    float d0 = x0 - mean, d1 = x1 - mean;
    float q = d0 * d0 + d1 * d1;
#pragma unroll
    for (int o = 32; o; o >>= 1) q += __shfl_xor(q, o);
    float sd = sqrtf(q / (float)(AN - 1));
    int pk = (int)(x0 < 0.f) + (int)(x1 < 0.f)
           + (((int)(x0 == 0.f) + (int)(x1 == 0.f)) << 10)
           + (((int)(x0 > 0.f) + (int)(x1 > 0.f)) << 20);
#pragma unroll
    for (int o = 32; o; o >>= 1) pk += __shfl_xor(pk, o);
    if (lane == 0) {
      int nn = pk & 1023, nz = (pk >> 10) & 1023, np = (pk >> 20) & 1023;
      a_conc += (double)nn * nn + (double)nz * nz + (double)np * np;
      a_sstd += (double)sd;
      if (t == 0) wsd[WS_STD0] = (double)sd;
      if (t == TN - 1) wsd[WS_STDL] = (double)sd;
    }
  }
  roll_strip4<20>(x, b * 16 + w * 4, NW20, lane, a_c20, a_s10l5 /*unused*/);
  roll_strip4<10>(x, b * 16 + w * 4, NW10, lane, a_s10, a_s10l5);
  if (lane == 0) {
    sm.tacc[w][0] = a_sstd; sm.tacc[w][1] = a_conc; sm.tacc[w][2] = a_c20;
    sm.tacc[w][3] = a_s10;  sm.tacc[w][4] = a_s10l5;
  }
  __syncthreads();
  if (tid == 0) {
#pragma unroll
    for (int j = 0; j < 5; ++j)
      wsd[WS_BLK + (size_t)b * 5 + j] =
          sm.tacc[0][j] + sm.tacc[1][j] + sm.tacc[2][j] + sm.tacc[3][j];
    __threadfence();
    __hip_atomic_store(&flagA[b], MAGICA, __ATOMIC_RELEASE,
                       __HIP_MEMORY_SCOPE_AGENT);
  }
  if (b < FOLD0) return;

  // ============== phase B: cov->corr fold (blocks 448..511) ============
  const int c = b - FOLD0;
  if (tid < NGRAM) {
    while (__hip_atomic_load(&flagG[tid], __ATOMIC_ACQUIRE,
                             __HIP_MEMORY_SCOPE_AGENT) != MAGICG)
      __builtin_amdgcn_s_sleep(2);
  }
  __syncthreads();
  __threadfence();
  if (tid < AN) {
    double cs = 0.0, dg = 0.0;
    for (int s = 0; s < NGRAM; ++s) {
      cs += (double)pc[s * AN + tid];
      dg += (double)pdg[s * AN + tid];
    }
    double mu = cs / (double)TN;
    sm.u.fold.muS[tid] = mu;
    sm.u.fold.dS[tid] = sqrt(dg - (double)TN * mu * mu);
  }
  __syncthreads();
  {
    int e = c * 256 + tid;
    int i = e >> 7, j = e & (AN - 1);
    double cv = 0.0;
    for (int s = 0; s < NGRAM; ++s) cv += (double)pg[(size_t)s * (AN * AN) + e];
    cv -= (double)TN * sm.u.fold.muS[i] * sm.u.fold.muS[j];
    double cc = cv / (sm.u.fold.dS[i] * sm.u.fold.dS[j]);
    corr[e] = (float)cc;
    sm.u.fold.r0[tid] = cc;
    sm.u.fold.r1[tid] = fabs(cc);
    sm.u.fold.r2[tid] = (i == j) ? cc : 0.0;
  }
  __syncthreads();
  for (int sft = 128; sft; sft >>= 1) {
    if (tid < sft) {
      sm.u.fold.r0[tid] += sm.u.fold.r0[tid + sft];
      sm.u.fold.r1[tid] += sm.u.fold.r1[tid + sft];
      sm.u.fold.r2[tid] += sm.u.fold.r2[tid + sft];
    }
    __syncthreads();
  }
  if (tid == 0) {
    wsd[WS_SPEC + c * 3 + 0] = sm.u.fold.r0[0];
    wsd[WS_SPEC + c * 3 + 1] = sm.u.fold.r1[0];
    wsd[WS_SPEC + c * 3 + 2] = sm.u.fold.r2[0];
    __threadfence();
    __hip_atomic_store(&flagB[c], MAGICB, __ATOMIC_RELEASE,
                       __HIP_MEMORY_SCOPE_AGENT);
  }
  if (b != GRID - 1) return;

  // ================= phase C: spec + MLP + assembly (block 511) ========
  while (__hip_atomic_load(&flagA[tid], __ATOMIC_ACQUIRE,
                           __HIP_MEMORY_SCOPE_AGENT) != MAGICA)
    __builtin_amdgcn_s_sleep(2);
  while (__hip_atomic_load(&flagA[tid + 256], __ATOMIC_ACQUIRE,
                           __HIP_MEMORY_SCOPE_AGENT) != MAGICA)
    __builtin_amdgcn_s_sleep(2);
  if (tid < NFOLD) {
    while (__hip_atomic_load(&flagB[tid], __ATOMIC_ACQUIRE,
                             __HIP_MEMORY_SCOPE_AGENT) != MAGICB)
      __builtin_amdgcn_s_sleep(2);
  }
  __syncthreads();
  __threadfence();
  // scalar folds over 512 block slots
  {
    double v0 = 0, v1 = 0, v2 = 0, v3 = 0, v4 = 0;
    for (int k = tid; k < GRID; k += 256) {
      const double* p = wsd + WS_BLK + (size_t)k * 5;
      v0 += p[0]; v1 += p[1]; v2 += p[2]; v3 += p[3]; v4 += p[4];
    }
    sm.u.scal.s0[tid] = v0; sm.u.scal.s1[tid] = v1; sm.u.scal.s2[tid] = v2;
    sm.u.scal.s3[tid] = v3; sm.u.scal.s4[tid] = v4;
    __syncthreads();
    for (int sft = 128; sft; sft >>= 1) {
      if (tid < sft) {
        sm.u.scal.s0[tid] += sm.u.scal.s0[tid + sft];
        sm.u.scal.s1[tid] += sm.u.scal.s1[tid + sft];
        sm.u.scal.s2[tid] += sm.u.scal.s2[tid + sft];
        sm.u.scal.s3[tid] += sm.u.scal.s3[tid + sft];
        sm.u.scal.s4[tid] += sm.u.scal.s4[tid + sft];
      }
      __syncthreads();
    }
    if (tid == 0) {
      sm.tiny[0] = sm.u.scal.s0[0]; sm.tiny[1] = sm.u.scal.s1[0];
      sm.tiny[2] = sm.u.scal.s2[0]; sm.tiny[3] = sm.u.scal.s3[0];
      sm.tiny[4] = sm.u.scal.s4[0];
    }
    __syncthreads();
  }
  {
    double v0 = 0, v1 = 0, v2 = 0;
    if (tid < NFOLD) {
      v0 = wsd[WS_SPEC + tid * 3 + 0];
      v1 = wsd[WS_SPEC + tid * 3 + 1];
      v2 = wsd[WS_SPEC + tid * 3 + 2];
    }
    sm.u.scal.s0[tid] = v0; sm.u.scal.s1[tid] = v1; sm.u.scal.s2[tid] = v2;
    __syncthreads();
    for (int sft = 128; sft; sft >>= 1) {
      if (tid < sft) {
        sm.u.scal.s0[tid] += sm.u.scal.s0[tid + sft];
        sm.u.scal.s1[tid] += sm.u.scal.s1[tid + sft];
        sm.u.scal.s2[tid] += sm.u.scal.s2[tid + sft];
      }
      __syncthreads();
    }
    if (tid == 0) {
      sm.tiny[5] = sm.u.scal.s0[0];
      sm.tiny[6] = sm.u.scal.s1[0];
      sm.tiny[7] = sm.u.scal.s2[0];
    }
    __syncthreads();
  }
  // corr -> LDS bf16, power iteration
  for (int e = tid; e < AN * AN; e += 256) {
    unsigned int ub = __float_as_uint(corr[e]);
    sm.u.spec.cS[(e >> 7) * 130 + (e & (AN - 1))] =
        (unsigned short)((ub + 0x8000u) >> 16);
  }
  if (tid < AN) sm.u.spec.vv[tid] = 1.0f;
  __syncthreads();
  int ri = tid & (AN - 1), hh = tid >> 7;
  float lam = 0.0f;
  for (int it = 0; it < 12; ++it) {
    float acc = 0.f;
    const unsigned short* rp = &sm.u.spec.cS[ri * 130 + hh * 64];
    const float* vp = &sm.u.spec.vv[hh * 64];
#pragma unroll
    for (int k = 0; k < 64; ++k)
      acc += __uint_as_float((unsigned int)rp[k] << 16) * vp[k];
    sm.u.spec.prt[tid] = acc;
    __syncthreads();
    if (tid < AN) {
      float u = sm.u.spec.prt[tid] + sm.u.spec.prt[tid + 128];
      sm.u.spec.un[tid] = u;
      sm.u.spec.red[tid] = u * u;
    }
    __syncthreads();
    for (int sft = 64; sft; sft >>= 1) {
      if (tid < sft) sm.u.spec.red[tid] += sm.u.spec.red[tid + sft];
      __syncthreads();
    }
    lam = sqrtf(sm.u.spec.red[0]);
    if (tid < AN) sm.u.spec.vv[tid] = sm.u.spec.un[tid] / lam;
    __syncthreads();
  }
  __syncthreads();
  // MLP
  sm.u.mlp.f[tid] = (tid < AN) ? x[(size_t)(TN - 1) * AN + tid] : pos[tid - AN];
  __syncthreads();
  if (tid < AN) {
    float acc = b1[tid];
    for (int k = 0; k < 2 * AN; ++k)
      acc = fmaf(sm.u.mlp.f[k], w1[k * AN + tid], acc);
    acc = fmaxf(acc, 0.0f);
    acc = gamma[tid] * (acc / sqrtf(1.0f + 1e-5f)) + beta[tid];
    sm.u.mlp.h1[tid] = acc;
  }
  __syncthreads();
  if (tid < 64) {
    float acc = b2[tid];
    for (int k = 0; k < AN; ++k)
      acc = fmaf(sm.u.mlp.h1[k], w2[k * 64 + tid], acc);
    sm.u.mlp.h2[tid] = fmaxf(acc, 0.0f);
  }
  __syncthreads();
  if (tid < 3) {
    float acc = b3[tid];
    for (int k = 0; k < 64; ++k)
      acc = fmaf(sm.u.mlp.h2[k], w3[k * 3 + tid], acc);
    sm.u.mlp.lg[tid] = acc;
  }
  __syncthreads();
  if (tid != 0) return;
  float m = fmaxf(sm.u.mlp.lg[0], fmaxf(sm.u.mlp.lg[1], sm.u.mlp.lg[2]));
  float e0 = expf(sm.u.mlp.lg[0] - m), e1 = expf(sm.u.mlp.lg[1] - m),
        e2 = expf(sm.u.mlp.lg[2] - m);
  double sev = (double)(e2 / (e0 + e1 + e2));
  double sumstd = sm.tiny[0], conc = sm.tiny[1], cnt20 = sm.tiny[2];
  double sum10 = sm.tiny[3], sum10l5 = sm.tiny[4];
  double csum = sm.tiny[5], cabs = sm.tiny[6], ctrace = sm.tiny[7];
  double avg_disp = sumstd / (double)TN;
  double trend = -(wsd[WS_STDL] - wsd[WS_STD0]) / (double)(TN - 1);
  double hi = trend / (avg_disp + 1e-6) + 0.5;
  hi = fmin(1.0, fmax(0.0, hi));
  double avg_corr = (csum - ctrace) / ((double)AN * (AN - 1));
  double sync_ind = (double)lam / (double)AN;
  double sync_risk = fmin(1.0, sync_ind * avg_corr);
  double pl = cnt20 / (double)(TN - 20);
  double rd = 1.0 - cabs / ((double)AN * AN);
  double pasum = 0.0, pamax = 0.0;
  for (int k = 0; k < AN; ++k) {
    double pa = fabs((double)pos[k]);
    pasum += pa;
    if (pa > pamax) pamax = pa;
  }
  double pd = 1.0 - pamax / pasum;
  double dl = 1.0 - sqrt(rd * pd);
  double recent = sum10l5 / 5.0;
  double hist = (sum10 - sum10l5) / (double)(TN - 10 - 5);
  double sraw = (recent - hist) / hist;
  sraw = fmin(1.0, fmax(0.0, sraw));
  double surge = (hist > 0.0) ? sraw : 0.0;
  double ac = (conc / (double)TN - (double)AN) / ((double)AN * (AN - 1));
  double pcup = fmin(1.0, fmax(0.0, (ac - 0.5) * 2.0));
  double cr = (hi + sync_risk + dl) / 3.0;
  out[0] = (float)hi;
  out[1] = (float)sev;
  out[2] = (float)sync_risk;
  out[3] = (float)pl;
  out[4] = (float)dl;
  out[5] = (float)surge;
  out[6] = (float)pcup;
  out[7] = (float)cr;
}

extern "C" void kernel_launch(void* const* d_in, const int* in_sizes, int n_in,
                              void* d_out, int out_size, void* d_ws, size_t ws_size,
                              hipStream_t stream) {
  const float* x     = (const float*)d_in[0];
  const float* pos   = (const float*)d_in[1];
  const float* w1    = (const float*)d_in[2];
  const float* b1    = (const float*)d_in[3];
  const float* gamma = (const float*)d_in[4];
  const float* beta  = (const float*)d_in[5];
  const float* w2    = (const float*)d_in[6];
  const float* b2    = (const float*)d_in[7];
  const float* w3    = (const float*)d_in[8];
  const float* b3    = (const float*)d_in[9];
  float* out = (float*)d_out;
  double* wsd = (double*)d_ws;
  float* corr = (float*)(wsd + WS_DEND);               // [16384]
  float* pc   = corr + AN * AN;                        // [128*128]
  float* pdg  = pc + NGRAM * AN;                       // [128*128]
  float* pg   = pdg + NGRAM * AN;                      // [128*16384]
  unsigned int* flagG = (unsigned int*)(pg + (size_t)NGRAM * AN * AN);
  unsigned int* flagA = flagG + NGRAM;
  unsigned int* flagB = flagA + GRID;

  k_all<<<GRID, 256, 0, stream>>>(x, pos, w1, b1, gamma, beta, w2, b2, w3, b3,
                                  wsd, corr, pc, pdg, pg, flagG, flagA, flagB,
                                  out);
}